// Round 7
// baseline (583.588 us; speedup 1.0000x reference)
//
#include <hip/hip_runtime.h>
#include <math.h>

#define CCH   50
#define HH    256
#define WW    256
#define BATCH 16
#define HSZ   64
#define WSZ   64
#define NTOP  240
#define SPX   66      // staged px per row (64 + 2 halo)
#define SROW  6       // staged rows (4 + 2 halo)

typedef __attribute__((ext_vector_type(8))) short s16x8;
typedef __attribute__((ext_vector_type(4))) float f32x4;

__device__ __forceinline__ unsigned short bf16rne(float x) {
  unsigned u = __float_as_uint(x);
  unsigned r = (u + 0x7FFFu + ((u >> 16) & 1u)) >> 16;
  return (unsigned short)r;
}
__device__ __forceinline__ float bf2f(unsigned short h) {
  return __uint_as_float(((unsigned)h) << 16);
}

// ---------------- Kernel 0: pack W1 into MFMA A-fragments (split bf16) ----
// combo = ((chunk*9 + tap)*4 + mt)*2 + sp ; per combo 64 lanes x 8 bf16.
// element (lane, e): co = mt*16 + (lane&15), ci = chunk*32 + (lane>>4)*8 + e.
__global__ __launch_bounds__(64) void prep_wfrag_k(
    const float* __restrict__ W1, unsigned short* __restrict__ wf) {
  int combo = blockIdx.x;            // 0..143
  int lane = threadIdx.x;
  int sp = combo & 1;
  int t2 = combo >> 1;
  int mt = t2 & 3;
  int t3 = t2 >> 2;                  // 0..17
  int tap = t3 % 9;
  int chunk = t3 / 9;
  int co = mt * 16 + (lane & 15);
  int gbase = combo * 512 + lane * 8;
#pragma unroll
  for (int e = 0; e < 8; ++e) {
    int ci = chunk * 32 + ((lane >> 4) * 8) + e;
    float w = (co < CCH && ci < CCH) ? W1[co * (CCH * 9) + ci * 9 + tap] : 0.f;
    unsigned short h = bf16rne(w);
    unsigned short v = sp ? bf16rne(w - bf2f(h)) : h;
    wf[gbase + e] = v;
  }
}

// ---------------- Kernel 1: conv3x3 (50->50) + ReLU via MFMA -------------
// Tile: 4 rows x 64 px, 4 waves; wave = 1 row x 64 px x all-64 co.
// LDS: [6 rows][66 px][hi32|lo32 ci shorts], 50.7 KB -> 3 blocks/CU.
// 16B-granule XOR swizzle (granule ^= px&7): staging b128 writes and
// B-frag b128 reads both near-conflict-free (proven in round 6).
// Output stored CHANNEL-LAST x1c[b][row][px][50ci] f32 for conv2 streaming.
__global__ __launch_bounds__(256, 3) void conv1_mfma_k(
    const float* __restrict__ in, const unsigned short* __restrict__ wf,
    const float* __restrict__ b1, float* __restrict__ x1c) {
  __shared__ alignas(16) short xlds[SROW * SPX * 64];   // 50,688 B

  int bx = blockIdx.x;
  int pq = bx & 3;                   // px quarter (64 px)
  int rg = (bx >> 2) & 63;           // row group (4 rows)
  int b  = bx >> 8;                  // batch
  int row0 = rg * 4;
  int px0g = pq * 64;

  int t = threadIdx.x;
  int lane = t & 63;
  int wv = t >> 6;                   // wave owns output row row0+wv
  int ln15 = lane & 15;
  int lg = lane >> 4;

  f32x4 acc[4][4];                   // [mt][s]
#pragma unroll
  for (int mt = 0; mt < 4; ++mt)
#pragma unroll
    for (int s = 0; s < 4; ++s) acc[mt][s] = (f32x4){0.f, 0.f, 0.f, 0.f};

  const size_t in_b = ((size_t)b * CCH) << 16;

#pragma unroll
  for (int chunk = 0; chunk < 2; ++chunk) {
    __syncthreads();                 // previous chunk's reads complete
    // ---- stage: item = (row, oct, px); lane loads 8 ci for one px ----
    for (int i = t; i < SROW * 4 * SPX; i += 256) {   // 1584 items
      int ro = i / SPX;              // row*4 + oct
      int px = i - ro * SPX;
      int row = ro >> 2, oct = ro & 3;
      int gr = row0 - 1 + row;
      int gx = px0g - 1 + px;
      bool okxy = (gr >= 0 && gr < HH && gx >= 0 && gx < WW);
      const float* gp = in + in_b + ((size_t)(chunk * 32 + oct * 8) << 16)
                        + (gr << 8) + gx;
      unsigned hs[8], ls[8];
#pragma unroll
      for (int e = 0; e < 8; ++e) {
        int ci = chunk * 32 + oct * 8 + e;
        float x = (okxy && ci < CCH) ? gp[(size_t)e << 16] : 0.f;
        unsigned u = __float_as_uint(x);
        unsigned hu = u & 0xFFFF0000u;          // trunc-split hi
        float lo = x - __uint_as_float(hu);     // exact residual
        unsigned ul = __float_as_uint(lo);
        hs[e] = hu >> 16;
        ls[e] = (ul + 0x7FFFu + ((ul >> 16) & 1u)) >> 16;   // rne lo
      }
      s16x8 hv, lv;
#pragma unroll
      for (int e = 0; e < 8; ++e) { hv[e] = (short)hs[e]; lv[e] = (short)ls[e]; }
      int swz = (px & 7) << 3;                  // 16B-granule XOR (8 shorts)
      int base_sh = (row * SPX + px) * 64;
      *(s16x8*)&xlds[base_sh + ((oct * 8) ^ swz)] = hv;
      *(s16x8*)&xlds[base_sh + ((32 + oct * 8) ^ swz)] = lv;
    }
    __syncthreads();

    // ---- 9 taps ----
#pragma unroll
    for (int tap = 0; tap < 9; ++tap) {
      const int dh = tap / 3 - 1;
      const int dw = tap % 3 - 1;
      // A fragments (all 4 co-tiles, hi+lo) — L2-hot global
      s16x8 ah[4], al[4];
#pragma unroll
      for (int mt = 0; mt < 4; ++mt) {
        int cb = ((chunk * 9 + tap) * 4 + mt) * 2;
        ah[mt] = *(const s16x8*)(wf + (size_t)cb * 512 + lane * 8);
        al[mt] = *(const s16x8*)(wf + (size_t)(cb + 1) * 512 + lane * 8);
      }
      int rbase = (wv + 1 + dh) * (SPX * 64);
#pragma unroll
      for (int s = 0; s < 4; ++s) {
        int pixL = 1 + s * 16 + ln15 + dw;
        int bsh = rbase + pixL * 64;
        int swz = (pixL & 7) << 3;
        s16x8 bh = *(const s16x8*)&xlds[bsh + ((lg * 8) ^ swz)];
        s16x8 bl = *(const s16x8*)&xlds[bsh + ((32 + lg * 8) ^ swz)];
#pragma unroll
        for (int mt = 0; mt < 4; ++mt) {
          acc[mt][s] = __builtin_amdgcn_mfma_f32_16x16x32_bf16(
              ah[mt], bh, acc[mt][s], 0, 0, 0);
          acc[mt][s] = __builtin_amdgcn_mfma_f32_16x16x32_bf16(
              ah[mt], bl, acc[mt][s], 0, 0, 0);
          acc[mt][s] = __builtin_amdgcn_mfma_f32_16x16x32_bf16(
              al[mt], bh, acc[mt][s], 0, 0, 0);
        }
      }
    }
  }

  // ---- epilogue: bias + ReLU, store channel-last f32 (C/D: col=lane&15,
  // row=(lane>>4)*4+reg) ----
  int orow = row0 + wv;
  size_t obase = (size_t)((b << 8) + orow) << 8;
#pragma unroll
  for (int s = 0; s < 4; ++s) {
    int px = px0g + s * 16 + ln15;
    float* op = x1c + (obase + px) * CCH;
#pragma unroll
    for (int mt = 0; mt < 4; ++mt) {
      int co0 = mt * 16 + lg * 4;
      if (co0 < 48) {
        float2 v01 = {fmaxf(acc[mt][s][0] + b1[co0], 0.f),
                      fmaxf(acc[mt][s][1] + b1[co0 + 1], 0.f)};
        float2 v23 = {fmaxf(acc[mt][s][2] + b1[co0 + 2], 0.f),
                      fmaxf(acc[mt][s][3] + b1[co0 + 3], 0.f)};
        *(float2*)&op[co0] = v01;
        *(float2*)&op[co0 + 2] = v23;
      } else if (co0 == 48) {
        float2 v01 = {fmaxf(acc[mt][s][0] + b1[48], 0.f),
                      fmaxf(acc[mt][s][1] + b1[49], 0.f)};
        *(float2*)&op[48] = v01;
      }
    }
  }
}

// ---------------- Kernel 2: conv3x3 (50->2) + softmax[:,1], channel-last --
// Thread = one pixel; 25 float2 ci-loads per tap (lane-contiguous, L1-hot);
// weights are wave-uniform s_loads (3.6 KB total, sL1-cached).
__global__ __launch_bounds__(256) void conv2_softmax_k(
    const float* __restrict__ x1c, const float* __restrict__ w2,
    const float* __restrict__ b2, float* __restrict__ sm) {
  int bx = blockIdx.x;               // b*256 + row
  int row = bx & 255;
  int px = threadIdx.x;
  float a0 = b2[0], a1 = b2[1];
#pragma unroll
  for (int tap = 0; tap < 9; ++tap) {
    const int dh = tap / 3 - 1, dw = tap % 3 - 1;
    int r = row + dh, c = px + dw;
    if (r >= 0 && r < HH && c >= 0 && c < WW) {
      const float* p = x1c + (size_t)(((bx >> 8) << 16) | (r << 8) | c) * CCH;
#pragma unroll
      for (int j = 0; j < 25; ++j) {
        float2 v = *(const float2*)&p[2 * j];
        a0 = fmaf(w2[(2 * j) * 9 + tap], v.x, a0);
        a0 = fmaf(w2[(2 * j + 1) * 9 + tap], v.y, a0);
        a1 = fmaf(w2[450 + (2 * j) * 9 + tap], v.x, a1);
        a1 = fmaf(w2[450 + (2 * j + 1) * 9 + tap], v.y, a1);
      }
    }
  }
  sm[((size_t)bx << 8) + px] = 1.f / (1.f + expf(a0 - a1));
}

// ---------------- Kernel 3: 4x4 avg pool + LeakyReLU(0.1) ----------------
__global__ __launch_bounds__(256) void pool_leaky_k(
    const float* __restrict__ sm, float* __restrict__ pool) {
  int idx = blockIdx.x * 256 + threadIdx.x;
  int b = idx >> 12, hw = idx & 4095;
  int hs = hw >> 6, ws = hw & 63;
  const float* p = sm + (size_t)b * 65536 + hs * 4 * WW + ws * 4;
  float s = 0.f;
#pragma unroll
  for (int r = 0; r < 4; ++r)
#pragma unroll
    for (int c = 0; c < 4; ++c) s += p[r * WW + c];
  s *= (1.f / 16.f);
  pool[idx] = (s >= 0.f) ? s : 0.1f * s;
}

// ---------------- Kernel 4: 25-tap learned mixing -> final_mask ----------------
__global__ __launch_bounds__(256) void mix_mask_k(
    const float* __restrict__ pool, const float* __restrict__ wk,
    const float* __restrict__ bk, float* __restrict__ mask_out) {
  int idx = blockIdx.x * 256 + threadIdx.x;
  int b = idx >> 12, hw = idx & 4095;
  int hs = hw >> 6, ws = hw & 63;
  float c = pool[idx];
  float s = 0.f;
#pragma unroll
  for (int i = 0; i < 5; ++i) {
#pragma unroll
    for (int j = 0; j < 5; ++j) {
      int y = hs + i - 2, x = ws + j - 2;
      float win = (y >= 0 && y < HSZ && x >= 0 && x < WSZ)
                      ? pool[(size_t)b * 4096 + y * WSZ + x] : 0.f;
      int k = i * 5 + j;
      s += (wk[k] * c + bk[k]) * win;
    }
  }
  mask_out[idx] = s;
}

// ---------------- Kernel 5: per-batch top-240 + ascending index sort ----------------
__global__ __launch_bounds__(256) void topk_sort_k(
    const float* __restrict__ mask, float* __restrict__ ob, float* __restrict__ oh,
    float* __restrict__ ow, int* __restrict__ idx_ws) {
  __shared__ unsigned long long keys[4096];
  __shared__ int sidx[256];
  int b = blockIdx.x, t = threadIdx.x;

  for (int i = t; i < 4096; i += 256) {
    float v = mask[(size_t)b * 4096 + i];
    unsigned u = __float_as_uint(v);
    u = (u & 0x80000000u) ? ~u : (u | 0x80000000u);
    u = ~u;
    keys[i] = ((unsigned long long)u << 12) | (unsigned)i;
  }
  __syncthreads();

  for (int k = 2; k <= 4096; k <<= 1) {
    for (int j = k >> 1; j > 0; j >>= 1) {
      for (int m = t; m < 2048; m += 256) {
        int i = ((m & ~(j - 1)) << 1) | (m & (j - 1));
        int l = i | j;
        bool up = ((i & k) == 0);
        unsigned long long a = keys[i], c = keys[l];
        if ((a > c) == up) { keys[i] = c; keys[l] = a; }
      }
      __syncthreads();
    }
  }

  sidx[t] = (t < NTOP) ? (int)(keys[t] & 0xFFFu) : 0x7FFFFFFF;
  __syncthreads();
  for (int k = 2; k <= 256; k <<= 1) {
    for (int j = k >> 1; j > 0; j >>= 1) {
      if (t < 128) {
        int i = ((t & ~(j - 1)) << 1) | (t & (j - 1));
        int l = i | j;
        bool up = ((i & k) == 0);
        int a = sidx[i], c = sidx[l];
        if ((a > c) == up) { sidx[i] = c; sidx[l] = a; }
      }
      __syncthreads();
    }
  }

  if (t < NTOP) {
    int id = sidx[t];
    int o = b * NTOP + t;
    ob[o] = (float)b;
    oh[o] = (float)(id >> 6);
    ow[o] = (float)(id & 63);
    idx_ws[o] = id;
  }
}

// ---------------- Kernel 6: gather 6x6 patches (pad=1, stride=4) ----------------
__global__ __launch_bounds__(256) void gather_patch_k(
    const float* __restrict__ in, const int* __restrict__ idx_ws,
    float* __restrict__ patches) {
  int p = blockIdx.x;
  int b = p / NTOP;
  int id = idx_ws[p];
  int h = id >> 6, w = id & 63;
  int y0 = h * 4 - 1, x0 = w * 4 - 1;
  const float* base = in + (size_t)b * CCH * 65536;
  float* op = patches + (size_t)p * (CCH * 36);
  for (int e = threadIdx.x; e < CCH * 36; e += 256) {
    int c = e / 36;
    int r = (e - c * 36) / 6;
    int col = e - c * 36 - r * 6;
    int y = y0 + r, x = x0 + col;
    float v = 0.f;
    if (y >= 0 && y < HH && x >= 0 && x < WW)
      v = base[(size_t)c * 65536 + y * WW + x];
    op[e] = v;
  }
}

extern "C" void kernel_launch(void* const* d_in, const int* in_sizes, int n_in,
                              void* d_out, int out_size, void* d_ws, size_t ws_size,
                              hipStream_t stream) {
  const float* out_lr = (const float*)d_in[0];
  const float* W1 = (const float*)d_in[1];
  const float* b1 = (const float*)d_in[2];
  const float* W2 = (const float*)d_in[3];
  const float* b2 = (const float*)d_in[4];
  const float* Wk = (const float*)d_in[5];
  const float* bk = (const float*)d_in[6];

  float* x1c  = (float*)d_ws;                 // 16*256*256*50 = 52,428,800
  float* sm   = x1c + (size_t)52428800;       // 16*256*256    =  1,048,576
  float* pool = sm + (size_t)1048576;         // 16*64*64      =     65,536
  int*  idxb  = (int*)(pool + 65536);         // 16*240        =      3,840
  unsigned short* wfrag = (unsigned short*)(pool + 65536 + 3840);  // 73,728 bf16

  float* out    = (float*)d_out;
  float* o_patch = out;                        // 3840*50*36
  float* o_b    = out + (size_t)6912000;
  float* o_h    = o_b + 3840;
  float* o_w    = o_h + 3840;
  float* o_mask = o_w + 3840;                  // 16*4096

  prep_wfrag_k<<<144, 64, 0, stream>>>(W1, wfrag);
  conv1_mfma_k<<<BATCH * 64 * 4, 256, 0, stream>>>(out_lr, wfrag, b1, x1c);
  conv2_softmax_k<<<BATCH * 256, 256, 0, stream>>>(x1c, W2, b2, sm);
  pool_leaky_k<<<256, 256, 0, stream>>>(sm, pool);
  mix_mask_k<<<256, 256, 0, stream>>>(pool, Wk, bk, o_mask);
  topk_sort_k<<<BATCH, 256, 0, stream>>>(o_mask, o_b, o_h, o_w, idxb);
  gather_patch_k<<<BATCH * NTOP, 256, 0, stream>>>(out_lr, idxb, o_patch);
}

// Round 8
// 518.614 us; speedup vs baseline: 1.1253x; 1.1253x over previous
//
#include <hip/hip_runtime.h>
#include <math.h>

#define CCH   50
#define HH    256
#define WW    256
#define BATCH 16
#define HSZ   64
#define WSZ   64
#define NTOP  240
#define SPX   66      // staged px per row (64 + 2 halo)
#define SROW  6       // staged rows (4 + 2 halo)

typedef __attribute__((ext_vector_type(8))) short s16x8;
typedef __attribute__((ext_vector_type(4))) float f32x4;

__device__ __forceinline__ unsigned short bf16rne(float x) {
  unsigned u = __float_as_uint(x);
  unsigned r = (u + 0x7FFFu + ((u >> 16) & 1u)) >> 16;
  return (unsigned short)r;
}
__device__ __forceinline__ float bf2f(unsigned short h) {
  return __uint_as_float(((unsigned)h) << 16);
}

// ---------------- Kernel 0: pack W1 into MFMA A-fragments (split bf16) ----
// combo = ((chunk*9 + tap)*4 + mt)*2 + sp ; per combo 64 lanes x 8 bf16.
// element (lane, e): co = mt*16 + (lane&15), ci = chunk*32 + (lane>>4)*8 + e.
__global__ __launch_bounds__(64) void prep_wfrag_k(
    const float* __restrict__ W1, unsigned short* __restrict__ wf) {
  int combo = blockIdx.x;            // 0..143
  int lane = threadIdx.x;
  int sp = combo & 1;
  int t2 = combo >> 1;
  int mt = t2 & 3;
  int t3 = t2 >> 2;                  // 0..17
  int tap = t3 % 9;
  int chunk = t3 / 9;
  int co = mt * 16 + (lane & 15);
  int gbase = combo * 512 + lane * 8;
#pragma unroll
  for (int e = 0; e < 8; ++e) {
    int ci = chunk * 32 + ((lane >> 4) * 8) + e;
    float w = (co < CCH && ci < CCH) ? W1[co * (CCH * 9) + ci * 9 + tap] : 0.f;
    unsigned short h = bf16rne(w);
    unsigned short v = sp ? bf16rne(w - bf2f(h)) : h;
    wf[gbase + e] = v;
  }
}

// ---------------- Kernel 1: conv3x3 (50->50) + ReLU via MFMA -------------
// Tile: 4 rows x 64 px, 4 waves; wave = 1 row x 64 px x all-64 co.
// LDS: [6 rows][66 px][hi32|lo32 ci shorts], 50.7 KB -> 3 blocks/CU.
// 16B-granule XOR swizzle (granule ^= px&7): staging b128 writes and
// B-frag b128 reads both near-conflict-free (proven in round 6).
// Output stored CHANNEL-LAST x1c[b][row][px][50ci] f32 for conv2 streaming.
__global__ __launch_bounds__(256, 3) void conv1_mfma_k(
    const float* __restrict__ in, const unsigned short* __restrict__ wf,
    const float* __restrict__ b1, float* __restrict__ x1c) {
  __shared__ alignas(16) short xlds[SROW * SPX * 64];   // 50,688 B

  int bx = blockIdx.x;
  int pq = bx & 3;                   // px quarter (64 px)
  int rg = (bx >> 2) & 63;           // row group (4 rows)
  int b  = bx >> 8;                  // batch
  int row0 = rg * 4;
  int px0g = pq * 64;

  int t = threadIdx.x;
  int lane = t & 63;
  int wv = t >> 6;                   // wave owns output row row0+wv
  int ln15 = lane & 15;
  int lg = lane >> 4;

  f32x4 acc[4][4];                   // [mt][s]
#pragma unroll
  for (int mt = 0; mt < 4; ++mt)
#pragma unroll
    for (int s = 0; s < 4; ++s) acc[mt][s] = (f32x4){0.f, 0.f, 0.f, 0.f};

  const size_t in_b = ((size_t)b * CCH) << 16;

#pragma unroll
  for (int chunk = 0; chunk < 2; ++chunk) {
    __syncthreads();                 // previous chunk's reads complete
    // ---- stage: item = (row, oct, px); lane loads 8 ci for one px ----
    for (int i = t; i < SROW * 4 * SPX; i += 256) {   // 1584 items
      int ro = i / SPX;              // row*4 + oct
      int px = i - ro * SPX;
      int row = ro >> 2, oct = ro & 3;
      int gr = row0 - 1 + row;
      int gx = px0g - 1 + px;
      bool okxy = (gr >= 0 && gr < HH && gx >= 0 && gx < WW);
      const float* gp = in + in_b + ((size_t)(chunk * 32 + oct * 8) << 16)
                        + (gr << 8) + gx;
      unsigned hs[8], ls[8];
#pragma unroll
      for (int e = 0; e < 8; ++e) {
        int ci = chunk * 32 + oct * 8 + e;
        float x = (okxy && ci < CCH) ? gp[(size_t)e << 16] : 0.f;
        unsigned u = __float_as_uint(x);
        unsigned hu = u & 0xFFFF0000u;          // trunc-split hi
        float lo = x - __uint_as_float(hu);     // exact residual
        unsigned ul = __float_as_uint(lo);
        hs[e] = hu >> 16;
        ls[e] = (ul + 0x7FFFu + ((ul >> 16) & 1u)) >> 16;   // rne lo
      }
      s16x8 hv, lv;
#pragma unroll
      for (int e = 0; e < 8; ++e) { hv[e] = (short)hs[e]; lv[e] = (short)ls[e]; }
      int swz = (px & 7) << 3;                  // 16B-granule XOR (8 shorts)
      int base_sh = (row * SPX + px) * 64;
      *(s16x8*)&xlds[base_sh + ((oct * 8) ^ swz)] = hv;
      *(s16x8*)&xlds[base_sh + ((32 + oct * 8) ^ swz)] = lv;
    }
    __syncthreads();

    // ---- 9 taps ----
#pragma unroll
    for (int tap = 0; tap < 9; ++tap) {
      const int dh = tap / 3 - 1;
      const int dw = tap % 3 - 1;
      // A fragments (all 4 co-tiles, hi+lo) — L2-hot global
      s16x8 ah[4], al[4];
#pragma unroll
      for (int mt = 0; mt < 4; ++mt) {
        int cb = ((chunk * 9 + tap) * 4 + mt) * 2;
        ah[mt] = *(const s16x8*)(wf + (size_t)cb * 512 + lane * 8);
        al[mt] = *(const s16x8*)(wf + (size_t)(cb + 1) * 512 + lane * 8);
      }
      int rbase = (wv + 1 + dh) * (SPX * 64);
#pragma unroll
      for (int s = 0; s < 4; ++s) {
        int pixL = 1 + s * 16 + ln15 + dw;
        int bsh = rbase + pixL * 64;
        int swz = (pixL & 7) << 3;
        s16x8 bh = *(const s16x8*)&xlds[bsh + ((lg * 8) ^ swz)];
        s16x8 bl = *(const s16x8*)&xlds[bsh + ((32 + lg * 8) ^ swz)];
#pragma unroll
        for (int mt = 0; mt < 4; ++mt) {
          acc[mt][s] = __builtin_amdgcn_mfma_f32_16x16x32_bf16(
              ah[mt], bh, acc[mt][s], 0, 0, 0);
          acc[mt][s] = __builtin_amdgcn_mfma_f32_16x16x32_bf16(
              ah[mt], bl, acc[mt][s], 0, 0, 0);
          acc[mt][s] = __builtin_amdgcn_mfma_f32_16x16x32_bf16(
              al[mt], bh, acc[mt][s], 0, 0, 0);
        }
      }
    }
  }

  // ---- epilogue: bias + ReLU, store channel-last f32 (C/D: col=lane&15,
  // row=(lane>>4)*4+reg) ----
  int orow = row0 + wv;
  size_t obase = (size_t)((b << 8) + orow) << 8;
#pragma unroll
  for (int s = 0; s < 4; ++s) {
    int px = px0g + s * 16 + ln15;
    float* op = x1c + (obase + px) * CCH;
#pragma unroll
    for (int mt = 0; mt < 4; ++mt) {
      int co0 = mt * 16 + lg * 4;
      if (co0 < 48) {
        float2 v01 = {fmaxf(acc[mt][s][0] + b1[co0], 0.f),
                      fmaxf(acc[mt][s][1] + b1[co0 + 1], 0.f)};
        float2 v23 = {fmaxf(acc[mt][s][2] + b1[co0 + 2], 0.f),
                      fmaxf(acc[mt][s][3] + b1[co0 + 3], 0.f)};
        *(float2*)&op[co0] = v01;
        *(float2*)&op[co0 + 2] = v23;
      } else if (co0 == 48) {
        float2 v01 = {fmaxf(acc[mt][s][0] + b1[48], 0.f),
                      fmaxf(acc[mt][s][1] + b1[49], 0.f)};
        *(float2*)&op[48] = v01;
      }
    }
  }
}

// ---------------- Kernel 2: conv3x3 (50->2) + softmax[:,1], channel-last --
// Block = 4 output rows x 256 px (thread = 1 column, 4 vertical outputs):
// 6 input rows feed 4 outputs from registers -> read volume 9x -> 1.5x.
// XCD-chunked bijective swizzle keeps vertically-adjacent row groups on the
// same XCD so halo rows hit that XCD's L2. Weights wave-uniform -> s_loads.
__global__ __launch_bounds__(256) void conv2_softmax_k(
    const float* __restrict__ x1c, const float* __restrict__ w2,
    const float* __restrict__ b2, float* __restrict__ sm) {
  int pb = blockIdx.x;                       // 1024 blocks = 8 XCD x 128
  int l = (pb & 7) * 128 + (pb >> 3);        // bijective chunked swizzle
  int b  = l >> 6;
  int rg = l & 63;
  int row0 = rg * 4;
  int px = threadIdx.x;

  float a00, a01, a02, a03, a10, a11, a12, a13;
  a00 = a01 = a02 = a03 = b2[0];
  a10 = a11 = a12 = a13 = b2[1];

  const float* xb = x1c + ((size_t)b << 16) * CCH;

  // output o consumes input row gr with tap-row T = gr - (row0+o) + 1.
#define TAPROW(T, AX, AY) { \
    AX = fmaf(wb[18 * j + 3 * (T)], v.x, AX); \
    AX = fmaf(wb[18 * j + 9 + 3 * (T)], v.y, AX); \
    AY = fmaf(wb[450 + 18 * j + 3 * (T)], v.x, AY); \
    AY = fmaf(wb[450 + 18 * j + 9 + 3 * (T)], v.y, AY); }

#define RRBLK(GR, ...) { \
    int gr = (GR); \
    if (gr >= 0 && gr < HH) { \
      for (int dw = -1; dw <= 1; ++dw) { \
        int gc = px + dw; \
        if (gc >= 0 && gc < WW) { \
          const float* pp = xb + (size_t)((gr << 8) + gc) * CCH; \
          const float* wb = w2 + (dw + 1); \
          _Pragma("unroll") \
          for (int j = 0; j < 25; ++j) { \
            float2 v = *(const float2*)&pp[2 * j]; \
            __VA_ARGS__ \
          } } } } }

  RRBLK(row0 - 1, TAPROW(0, a00, a10))
  RRBLK(row0    , TAPROW(0, a01, a11) TAPROW(1, a00, a10))
  RRBLK(row0 + 1, TAPROW(0, a02, a12) TAPROW(1, a01, a11) TAPROW(2, a00, a10))
  RRBLK(row0 + 2, TAPROW(0, a03, a13) TAPROW(1, a02, a12) TAPROW(2, a01, a11))
  RRBLK(row0 + 3, TAPROW(1, a03, a13) TAPROW(2, a02, a12))
  RRBLK(row0 + 4, TAPROW(2, a03, a13))
#undef RRBLK
#undef TAPROW

  size_t so = ((size_t)b << 16) + (row0 << 8) + px;
  sm[so]       = 1.f / (1.f + expf(a00 - a10));
  sm[so + 256] = 1.f / (1.f + expf(a01 - a11));
  sm[so + 512] = 1.f / (1.f + expf(a02 - a12));
  sm[so + 768] = 1.f / (1.f + expf(a03 - a13));
}

// ---------------- Kernel 3: 4x4 avg pool + LeakyReLU(0.1) ----------------
__global__ __launch_bounds__(256) void pool_leaky_k(
    const float* __restrict__ sm, float* __restrict__ pool) {
  int idx = blockIdx.x * 256 + threadIdx.x;
  int b = idx >> 12, hw = idx & 4095;
  int hs = hw >> 6, ws = hw & 63;
  const float* p = sm + (size_t)b * 65536 + hs * 4 * WW + ws * 4;
  float s = 0.f;
#pragma unroll
  for (int r = 0; r < 4; ++r)
#pragma unroll
    for (int c = 0; c < 4; ++c) s += p[r * WW + c];
  s *= (1.f / 16.f);
  pool[idx] = (s >= 0.f) ? s : 0.1f * s;
}

// ---------------- Kernel 4: 25-tap learned mixing -> final_mask ----------------
__global__ __launch_bounds__(256) void mix_mask_k(
    const float* __restrict__ pool, const float* __restrict__ wk,
    const float* __restrict__ bk, float* __restrict__ mask_out) {
  int idx = blockIdx.x * 256 + threadIdx.x;
  int b = idx >> 12, hw = idx & 4095;
  int hs = hw >> 6, ws = hw & 63;
  float c = pool[idx];
  float s = 0.f;
#pragma unroll
  for (int i = 0; i < 5; ++i) {
#pragma unroll
    for (int j = 0; j < 5; ++j) {
      int y = hs + i - 2, x = ws + j - 2;
      float win = (y >= 0 && y < HSZ && x >= 0 && x < WSZ)
                      ? pool[(size_t)b * 4096 + y * WSZ + x] : 0.f;
      int k = i * 5 + j;
      s += (wk[k] * c + bk[k]) * win;
    }
  }
  mask_out[idx] = s;
}

// ---------------- Kernel 5: per-batch top-240 + ascending index sort ----------------
__global__ __launch_bounds__(256) void topk_sort_k(
    const float* __restrict__ mask, float* __restrict__ ob, float* __restrict__ oh,
    float* __restrict__ ow, int* __restrict__ idx_ws) {
  __shared__ unsigned long long keys[4096];
  __shared__ int sidx[256];
  int b = blockIdx.x, t = threadIdx.x;

  for (int i = t; i < 4096; i += 256) {
    float v = mask[(size_t)b * 4096 + i];
    unsigned u = __float_as_uint(v);
    u = (u & 0x80000000u) ? ~u : (u | 0x80000000u);
    u = ~u;
    keys[i] = ((unsigned long long)u << 12) | (unsigned)i;
  }
  __syncthreads();

  for (int k = 2; k <= 4096; k <<= 1) {
    for (int j = k >> 1; j > 0; j >>= 1) {
      for (int m = t; m < 2048; m += 256) {
        int i = ((m & ~(j - 1)) << 1) | (m & (j - 1));
        int l = i | j;
        bool up = ((i & k) == 0);
        unsigned long long a = keys[i], c = keys[l];
        if ((a > c) == up) { keys[i] = c; keys[l] = a; }
      }
      __syncthreads();
    }
  }

  sidx[t] = (t < NTOP) ? (int)(keys[t] & 0xFFFu) : 0x7FFFFFFF;
  __syncthreads();
  for (int k = 2; k <= 256; k <<= 1) {
    for (int j = k >> 1; j > 0; j >>= 1) {
      if (t < 128) {
        int i = ((t & ~(j - 1)) << 1) | (t & (j - 1));
        int l = i | j;
        bool up = ((i & k) == 0);
        int a = sidx[i], c = sidx[l];
        if ((a > c) == up) { sidx[i] = c; sidx[l] = a; }
      }
      __syncthreads();
    }
  }

  if (t < NTOP) {
    int id = sidx[t];
    int o = b * NTOP + t;
    ob[o] = (float)b;
    oh[o] = (float)(id >> 6);
    ow[o] = (float)(id & 63);
    idx_ws[o] = id;
  }
}

// ---------------- Kernel 6: gather 6x6 patches (pad=1, stride=4) ----------------
__global__ __launch_bounds__(256) void gather_patch_k(
    const float* __restrict__ in, const int* __restrict__ idx_ws,
    float* __restrict__ patches) {
  int p = blockIdx.x;
  int b = p / NTOP;
  int id = idx_ws[p];
  int h = id >> 6, w = id & 63;
  int y0 = h * 4 - 1, x0 = w * 4 - 1;
  const float* base = in + (size_t)b * CCH * 65536;
  float* op = patches + (size_t)p * (CCH * 36);
  for (int e = threadIdx.x; e < CCH * 36; e += 256) {
    int c = e / 36;
    int r = (e - c * 36) / 6;
    int col = e - c * 36 - r * 6;
    int y = y0 + r, x = x0 + col;
    float v = 0.f;
    if (y >= 0 && y < HH && x >= 0 && x < WW)
      v = base[(size_t)c * 65536 + y * WW + x];
    op[e] = v;
  }
}

extern "C" void kernel_launch(void* const* d_in, const int* in_sizes, int n_in,
                              void* d_out, int out_size, void* d_ws, size_t ws_size,
                              hipStream_t stream) {
  const float* out_lr = (const float*)d_in[0];
  const float* W1 = (const float*)d_in[1];
  const float* b1 = (const float*)d_in[2];
  const float* W2 = (const float*)d_in[3];
  const float* b2 = (const float*)d_in[4];
  const float* Wk = (const float*)d_in[5];
  const float* bk = (const float*)d_in[6];

  float* x1c  = (float*)d_ws;                 // 16*256*256*50 = 52,428,800
  float* sm   = x1c + (size_t)52428800;       // 16*256*256    =  1,048,576
  float* pool = sm + (size_t)1048576;         // 16*64*64      =     65,536
  int*  idxb  = (int*)(pool + 65536);         // 16*240        =      3,840
  unsigned short* wfrag = (unsigned short*)(pool + 65536 + 3840);  // 73,728 bf16

  float* out    = (float*)d_out;
  float* o_patch = out;                        // 3840*50*36
  float* o_b    = out + (size_t)6912000;
  float* o_h    = o_b + 3840;
  float* o_w    = o_h + 3840;
  float* o_mask = o_w + 3840;                  // 16*4096

  prep_wfrag_k<<<144, 64, 0, stream>>>(W1, wfrag);
  conv1_mfma_k<<<BATCH * 64 * 4, 256, 0, stream>>>(out_lr, wfrag, b1, x1c);
  conv2_softmax_k<<<BATCH * 64, 256, 0, stream>>>(x1c, W2, b2, sm);
  pool_leaky_k<<<256, 256, 0, stream>>>(sm, pool);
  mix_mask_k<<<256, 256, 0, stream>>>(pool, Wk, bk, o_mask);
  topk_sort_k<<<BATCH, 256, 0, stream>>>(o_mask, o_b, o_h, o_w, idxb);
  gather_patch_k<<<BATCH * NTOP, 256, 0, stream>>>(out_lr, idxb, o_patch);
}

// Round 10
// 434.811 us; speedup vs baseline: 1.3422x; 1.1927x over previous
//
#include <hip/hip_runtime.h>
#include <math.h>

#define CCH   50
#define HH    256
#define WW    256
#define BATCH 16
#define HSZ   64
#define WSZ   64
#define NTOP  240
#define SPX   66      // staged px per row (64 + 2 halo)
#define SROW  6       // staged rows (4 + 2 halo)

typedef __attribute__((ext_vector_type(8))) short s16x8;
typedef __attribute__((ext_vector_type(4))) float f32x4;

__device__ __forceinline__ unsigned short bf16rne(float x) {
  unsigned u = __float_as_uint(x);
  unsigned r = (u + 0x7FFFu + ((u >> 16) & 1u)) >> 16;
  return (unsigned short)r;
}
__device__ __forceinline__ float bf2f(unsigned short h) {
  return __uint_as_float(((unsigned)h) << 16);
}

// ---------------- Kernel 0: pack W1 into MFMA A-fragments (split bf16) ----
__global__ __launch_bounds__(64) void prep_wfrag_k(
    const float* __restrict__ W1, unsigned short* __restrict__ wf) {
  int combo = blockIdx.x;            // 0..143
  int lane = threadIdx.x;
  int sp = combo & 1;
  int t2 = combo >> 1;
  int mt = t2 & 3;
  int t3 = t2 >> 2;                  // 0..17
  int tap = t3 % 9;
  int chunk = t3 / 9;
  int co = mt * 16 + (lane & 15);
  int gbase = combo * 512 + lane * 8;
#pragma unroll
  for (int e = 0; e < 8; ++e) {
    int ci = chunk * 32 + ((lane >> 4) * 8) + e;
    float w = (co < CCH && ci < CCH) ? W1[co * (CCH * 9) + ci * 9 + tap] : 0.f;
    unsigned short h = bf16rne(w);
    unsigned short v = sp ? bf16rne(w - bf2f(h)) : h;
    wf[gbase + e] = v;
  }
}

// ---------------- Kernel 1: conv3x3 (50->50) + ReLU via MFMA -------------
// Tile: 4 rows x 64 px, 4 waves; wave = 1 row x 64 px x all-64 co.
// LDS: [6 rows][66 px][hi32|lo32 ci shorts], 50.7 KB -> 3 blocks/CU.
// 16B-granule XOR swizzle: staging writes & B-reads conflict-free (r6/r8).
// Output: PLANAR f32 x1p[b][co][row][px] (lane-dense stores; f32 keeps
// conv2 noise correlated -> top-240 selection stable — r9 lesson).
__global__ __launch_bounds__(256, 3) void conv1_mfma_k(
    const float* __restrict__ in, const unsigned short* __restrict__ wf,
    const float* __restrict__ b1, float* __restrict__ x1p) {
  __shared__ alignas(16) short xlds[SROW * SPX * 64];   // 50,688 B

  int bx = blockIdx.x;
  int pq = bx & 3;                   // px quarter (64 px)
  int rg = (bx >> 2) & 63;           // row group (4 rows)
  int b  = bx >> 8;                  // batch
  int row0 = rg * 4;
  int px0g = pq * 64;

  int t = threadIdx.x;
  int lane = t & 63;
  int wv = t >> 6;                   // wave owns output row row0+wv
  int ln15 = lane & 15;
  int lg = lane >> 4;

  f32x4 acc[4][4];                   // [mt][s]
#pragma unroll
  for (int mt = 0; mt < 4; ++mt)
#pragma unroll
    for (int s = 0; s < 4; ++s) acc[mt][s] = (f32x4){0.f, 0.f, 0.f, 0.f};

  const size_t in_b = ((size_t)b * CCH) << 16;

#pragma unroll
  for (int chunk = 0; chunk < 2; ++chunk) {
    __syncthreads();                 // previous chunk's reads complete
    // ---- stage: item = (row, oct, px); lane loads 8 ci for one px ----
    for (int i = t; i < SROW * 4 * SPX; i += 256) {   // 1584 items
      int ro = i / SPX;              // row*4 + oct
      int px = i - ro * SPX;
      int row = ro >> 2, oct = ro & 3;
      int gr = row0 - 1 + row;
      int gx = px0g - 1 + px;
      bool okxy = (gr >= 0 && gr < HH && gx >= 0 && gx < WW);
      const float* gp = in + in_b + ((size_t)(chunk * 32 + oct * 8) << 16)
                        + (gr << 8) + gx;
      unsigned hs[8], ls[8];
#pragma unroll
      for (int e = 0; e < 8; ++e) {
        int ci = chunk * 32 + oct * 8 + e;
        float x = (okxy && ci < CCH) ? gp[(size_t)e << 16] : 0.f;
        unsigned u = __float_as_uint(x);
        unsigned hu = u & 0xFFFF0000u;          // trunc-split hi
        float lo = x - __uint_as_float(hu);     // exact residual
        unsigned ul = __float_as_uint(lo);
        hs[e] = hu >> 16;
        ls[e] = (ul + 0x7FFFu + ((ul >> 16) & 1u)) >> 16;   // rne lo
      }
      s16x8 hv, lv;
#pragma unroll
      for (int e = 0; e < 8; ++e) { hv[e] = (short)hs[e]; lv[e] = (short)ls[e]; }
      int swz = (px & 7) << 3;                  // 16B-granule XOR (8 shorts)
      int base_sh = (row * SPX + px) * 64;
      *(s16x8*)&xlds[base_sh + ((oct * 8) ^ swz)] = hv;
      *(s16x8*)&xlds[base_sh + ((32 + oct * 8) ^ swz)] = lv;
    }
    __syncthreads();

    // ---- 9 taps ----
#pragma unroll
    for (int tap = 0; tap < 9; ++tap) {
      const int dh = tap / 3 - 1;
      const int dw = tap % 3 - 1;
      s16x8 ah[4], al[4];
#pragma unroll
      for (int mt = 0; mt < 4; ++mt) {
        int cb = ((chunk * 9 + tap) * 4 + mt) * 2;
        ah[mt] = *(const s16x8*)(wf + (size_t)cb * 512 + lane * 8);
        al[mt] = *(const s16x8*)(wf + (size_t)(cb + 1) * 512 + lane * 8);
      }
      int rbase = (wv + 1 + dh) * (SPX * 64);
#pragma unroll
      for (int s = 0; s < 4; ++s) {
        int pixL = 1 + s * 16 + ln15 + dw;
        int bsh = rbase + pixL * 64;
        int swz = (pixL & 7) << 3;
        s16x8 bh = *(const s16x8*)&xlds[bsh + ((lg * 8) ^ swz)];
        s16x8 bl = *(const s16x8*)&xlds[bsh + ((32 + lg * 8) ^ swz)];
#pragma unroll
        for (int mt = 0; mt < 4; ++mt) {
          acc[mt][s] = __builtin_amdgcn_mfma_f32_16x16x32_bf16(
              ah[mt], bh, acc[mt][s], 0, 0, 0);
          acc[mt][s] = __builtin_amdgcn_mfma_f32_16x16x32_bf16(
              ah[mt], bl, acc[mt][s], 0, 0, 0);
          acc[mt][s] = __builtin_amdgcn_mfma_f32_16x16x32_bf16(
              al[mt], bh, acc[mt][s], 0, 0, 0);
        }
      }
    }
  }

  // ---- epilogue: bias + ReLU -> planar f32 (C/D: col=lane&15,
  // row=(lane>>4)*4+reg) ----
  int orow = row0 + wv;
#pragma unroll
  for (int s = 0; s < 4; ++s) {
    int px = px0g + s * 16 + ln15;
#pragma unroll
    for (int mt = 0; mt < 4; ++mt) {
#pragma unroll
      for (int reg = 0; reg < 4; ++reg) {
        int co = mt * 16 + lg * 4 + reg;
        if (co < CCH) {
          float v = fmaxf(acc[mt][s][reg] + b1[co], 0.f);
          x1p[(((size_t)b * CCH + co) << 16) + (orow << 8) + px] = v;
        }
      }
    }
  }
}

// ---------------- Kernel 2: conv3x3 (50->2) + softmax[:,1], planar f32 ---
// Thread = 1 column x 4 output rows; per ci: 6 rows x 3 cols loaded once,
// all loads lane-consecutive (dense lines — no CL transaction blowup).
// XCD-chunked bijective swizzle: halo rows L2-hit across adjacent blocks.
__global__ __launch_bounds__(256) void conv2_softmax_k(
    const float* __restrict__ x1p, const float* __restrict__ w2,
    const float* __restrict__ b2, float* __restrict__ sm) {
  int pb = blockIdx.x;                       // 1024 blocks = 8 XCD x 128
  int l = (pb & 7) * 128 + (pb >> 3);        // bijective chunked swizzle
  int b  = l >> 6;
  int rg = l & 63;
  int row0 = rg * 4;
  int px = threadIdx.x;

  float a0, a1, a2, a3, c0, c1, c2, c3;      // ch0 / ch1 per output row
  a0 = a1 = a2 = a3 = b2[0];
  c0 = c1 = c2 = c3 = b2[1];
  bool wm = px > 0, wp = px < WW - 1;

  const float* xb = x1p + (((size_t)b * CCH) << 16);

#define TAP(T, A, C) { \
    A = fmaf(wc0[3 * (T)], lf, A); A = fmaf(wc0[3 * (T) + 1], m, A); \
    A = fmaf(wc0[3 * (T) + 2], rt, A); \
    C = fmaf(wc1[3 * (T)], lf, C); C = fmaf(wc1[3 * (T) + 1], m, C); \
    C = fmaf(wc1[3 * (T) + 2], rt, C); }

#define ROW(IR, BODY) { \
    int gr = row0 - 1 + (IR); \
    if (gr >= 0 && gr < HH) { \
      const float* rp = xp + (gr << 8); \
      float m  = rp[px]; \
      float lf = wm ? rp[px - 1] : 0.f; \
      float rt = wp ? rp[px + 1] : 0.f; \
      BODY \
    } }

  for (int ci = 0; ci < CCH; ++ci) {
    const float* xp = xb + ((size_t)ci << 16);
    const float* wc0 = w2 + ci * 9;
    const float* wc1 = w2 + 450 + ci * 9;
    ROW(0, TAP(0, a0, c0))
    ROW(1, TAP(0, a1, c1) TAP(1, a0, c0))
    ROW(2, TAP(0, a2, c2) TAP(1, a1, c1) TAP(2, a0, c0))
    ROW(3, TAP(0, a3, c3) TAP(1, a2, c2) TAP(2, a1, c1))
    ROW(4, TAP(1, a3, c3) TAP(2, a2, c2))
    ROW(5, TAP(2, a3, c3))
  }
#undef ROW
#undef TAP

  size_t so = ((size_t)b << 16) + (row0 << 8) + px;
  sm[so]       = 1.f / (1.f + expf(a0 - c0));
  sm[so + 256] = 1.f / (1.f + expf(a1 - c1));
  sm[so + 512] = 1.f / (1.f + expf(a2 - c2));
  sm[so + 768] = 1.f / (1.f + expf(a3 - c3));
}

// ---------------- Kernel 3: 4x4 avg pool + LeakyReLU(0.1) ----------------
__global__ __launch_bounds__(256) void pool_leaky_k(
    const float* __restrict__ sm, float* __restrict__ pool) {
  int idx = blockIdx.x * 256 + threadIdx.x;
  int b = idx >> 12, hw = idx & 4095;
  int hs = hw >> 6, ws = hw & 63;
  const float* p = sm + (size_t)b * 65536 + hs * 4 * WW + ws * 4;
  float s = 0.f;
#pragma unroll
  for (int r = 0; r < 4; ++r)
#pragma unroll
    for (int c = 0; c < 4; ++c) s += p[r * WW + c];
  s *= (1.f / 16.f);
  pool[idx] = (s >= 0.f) ? s : 0.1f * s;
}

// ---------------- Kernel 4: 25-tap learned mixing -> final_mask ----------------
__global__ __launch_bounds__(256) void mix_mask_k(
    const float* __restrict__ pool, const float* __restrict__ wk,
    const float* __restrict__ bk, float* __restrict__ mask_out) {
  int idx = blockIdx.x * 256 + threadIdx.x;
  int b = idx >> 12, hw = idx & 4095;
  int hs = hw >> 6, ws = hw & 63;
  float c = pool[idx];
  float s = 0.f;
#pragma unroll
  for (int i = 0; i < 5; ++i) {
#pragma unroll
    for (int j = 0; j < 5; ++j) {
      int y = hs + i - 2, x = ws + j - 2;
      float win = (y >= 0 && y < HSZ && x >= 0 && x < WSZ)
                      ? pool[(size_t)b * 4096 + y * WSZ + x] : 0.f;
      int k = i * 5 + j;
      s += (wk[k] * c + bk[k]) * win;
    }
  }
  mask_out[idx] = s;
}

// ---------------- Kernel 5: per-batch top-240 + ascending index sort ----------------
__global__ __launch_bounds__(256) void topk_sort_k(
    const float* __restrict__ mask, float* __restrict__ ob, float* __restrict__ oh,
    float* __restrict__ ow, int* __restrict__ idx_ws) {
  __shared__ unsigned long long keys[4096];
  __shared__ int sidx[256];
  int b = blockIdx.x, t = threadIdx.x;

  for (int i = t; i < 4096; i += 256) {
    float v = mask[(size_t)b * 4096 + i];
    unsigned u = __float_as_uint(v);
    u = (u & 0x80000000u) ? ~u : (u | 0x80000000u);
    u = ~u;
    keys[i] = ((unsigned long long)u << 12) | (unsigned)i;
  }
  __syncthreads();

  for (int k = 2; k <= 4096; k <<= 1) {
    for (int j = k >> 1; j > 0; j >>= 1) {
      for (int m = t; m < 2048; m += 256) {
        int i = ((m & ~(j - 1)) << 1) | (m & (j - 1));
        int l = i | j;
        bool up = ((i & k) == 0);
        unsigned long long a = keys[i], c = keys[l];
        if ((a > c) == up) { keys[i] = c; keys[l] = a; }
      }
      __syncthreads();
    }
  }

  sidx[t] = (t < NTOP) ? (int)(keys[t] & 0xFFFu) : 0x7FFFFFFF;
  __syncthreads();
  for (int k = 2; k <= 256; k <<= 1) {
    for (int j = k >> 1; j > 0; j >>= 1) {
      if (t < 128) {
        int i = ((t & ~(j - 1)) << 1) | (t & (j - 1));
        int l = i | j;
        bool up = ((i & k) == 0);
        int a = sidx[i], c = sidx[l];
        if ((a > c) == up) { sidx[i] = c; sidx[l] = a; }
      }
      __syncthreads();
    }
  }

  if (t < NTOP) {
    int id = sidx[t];
    int o = b * NTOP + t;
    ob[o] = (float)b;
    oh[o] = (float)(id >> 6);
    ow[o] = (float)(id & 63);
    idx_ws[o] = id;
  }
}

// ---------------- Kernel 6: gather 6x6 patches (pad=1, stride=4) ----------------
__global__ __launch_bounds__(256) void gather_patch_k(
    const float* __restrict__ in, const int* __restrict__ idx_ws,
    float* __restrict__ patches) {
  int p = blockIdx.x;
  int b = p / NTOP;
  int id = idx_ws[p];
  int h = id >> 6, w = id & 63;
  int y0 = h * 4 - 1, x0 = w * 4 - 1;
  const float* base = in + (size_t)b * CCH * 65536;
  float* op = patches + (size_t)p * (CCH * 36);
  for (int e = threadIdx.x; e < CCH * 36; e += 256) {
    int c = e / 36;
    int r = (e - c * 36) / 6;
    int col = e - c * 36 - r * 6;
    int y = y0 + r, x = x0 + col;
    float v = 0.f;
    if (y >= 0 && y < HH && x >= 0 && x < WW)
      v = base[(size_t)c * 65536 + y * WW + x];
    op[e] = v;
  }
}

extern "C" void kernel_launch(void* const* d_in, const int* in_sizes, int n_in,
                              void* d_out, int out_size, void* d_ws, size_t ws_size,
                              hipStream_t stream) {
  const float* out_lr = (const float*)d_in[0];
  const float* W1 = (const float*)d_in[1];
  const float* b1 = (const float*)d_in[2];
  const float* W2 = (const float*)d_in[3];
  const float* b2 = (const float*)d_in[4];
  const float* Wk = (const float*)d_in[5];
  const float* bk = (const float*)d_in[6];

  float* x1p  = (float*)d_ws;                 // 16*50*256*256 f32
  float* sm   = x1p + (size_t)52428800;       // 16*256*256
  float* pool = sm + (size_t)1048576;         // 16*64*64
  int*  idxb  = (int*)(pool + 65536);         // 16*240
  unsigned short* wfrag = (unsigned short*)(pool + 65536 + 3840);  // 73,728 bf16

  float* out    = (float*)d_out;
  float* o_patch = out;                        // 3840*50*36
  float* o_b    = out + (size_t)6912000;
  float* o_h    = o_b + 3840;
  float* o_w    = o_h + 3840;
  float* o_mask = o_w + 3840;                  // 16*4096

  prep_wfrag_k<<<144, 64, 0, stream>>>(W1, wfrag);
  conv1_mfma_k<<<BATCH * 64 * 4, 256, 0, stream>>>(out_lr, wfrag, b1, x1p);
  conv2_softmax_k<<<BATCH * 64, 256, 0, stream>>>(x1p, W2, b2, sm);
  pool_leaky_k<<<256, 256, 0, stream>>>(sm, pool);
  mix_mask_k<<<256, 256, 0, stream>>>(pool, Wk, bk, o_mask);
  topk_sort_k<<<BATCH, 256, 0, stream>>>(o_mask, o_b, o_h, o_w, idxb);
  gather_patch_k<<<BATCH * NTOP, 256, 0, stream>>>(out_lr, idxb, o_patch);
}

// Round 11
// 389.979 us; speedup vs baseline: 1.4965x; 1.1150x over previous
//
#include <hip/hip_runtime.h>
#include <math.h>

#define CCH   50
#define HH    256
#define WW    256
#define BATCH 16
#define HSZ   64
#define WSZ   64
#define NTOP  240
#define SPX   66      // staged px per row (64 + 2 halo)
#define SROW  6       // staged rows (4 + 2 halo)

typedef __attribute__((ext_vector_type(8))) short s16x8;
typedef __attribute__((ext_vector_type(4))) float f32x4;

__device__ __forceinline__ unsigned short bf16rne(float x) {
  unsigned u = __float_as_uint(x);
  unsigned r = (u + 0x7FFFu + ((u >> 16) & 1u)) >> 16;
  return (unsigned short)r;
}
__device__ __forceinline__ float bf2f(unsigned short h) {
  return __uint_as_float(((unsigned)h) << 16);
}

// ---------------- Kernel 0: pack W1 into MFMA A-fragments (split bf16) ----
__global__ __launch_bounds__(64) void prep_wfrag_k(
    const float* __restrict__ W1, unsigned short* __restrict__ wf) {
  int combo = blockIdx.x;            // 0..143
  int lane = threadIdx.x;
  int sp = combo & 1;
  int t2 = combo >> 1;
  int mt = t2 & 3;
  int t3 = t2 >> 2;                  // 0..17
  int tap = t3 % 9;
  int chunk = t3 / 9;
  int co = mt * 16 + (lane & 15);
  int gbase = combo * 512 + lane * 8;
#pragma unroll
  for (int e = 0; e < 8; ++e) {
    int ci = chunk * 32 + ((lane >> 4) * 8) + e;
    float w = (co < CCH && ci < CCH) ? W1[co * (CCH * 9) + ci * 9 + tap] : 0.f;
    unsigned short h = bf16rne(w);
    unsigned short v = sp ? bf16rne(w - bf2f(h)) : h;
    wf[gbase + e] = v;
  }
}

// ---------------- Kernel 1: conv3x3 (50->50) + ReLU via MFMA -------------
// Tile: 4 rows x 64 px, 4 waves; wave = 1 row x 64 px x all-64 co.
// LDS: [6 rows][66 px][hi32|lo32 ci shorts], 50.7 KB -> 3 blocks/CU.
// 16B-granule XOR swizzle: staging writes & B-reads conflict-free.
// setprio(1) around MFMA clusters (T5: staggered blocks on a CU).
// Output: PLANAR f32 x1p[b][co][row][px] (r9 lesson: keep f32).
__global__ __launch_bounds__(256, 3) void conv1_mfma_k(
    const float* __restrict__ in, const unsigned short* __restrict__ wf,
    const float* __restrict__ b1, float* __restrict__ x1p) {
  __shared__ alignas(16) short xlds[SROW * SPX * 64];   // 50,688 B

  int bx = blockIdx.x;
  int pq = bx & 3;                   // px quarter (64 px)
  int rg = (bx >> 2) & 63;           // row group (4 rows)
  int b  = bx >> 8;                  // batch
  int row0 = rg * 4;
  int px0g = pq * 64;

  int t = threadIdx.x;
  int lane = t & 63;
  int wv = t >> 6;                   // wave owns output row row0+wv
  int ln15 = lane & 15;
  int lg = lane >> 4;

  f32x4 acc[4][4];                   // [mt][s]
#pragma unroll
  for (int mt = 0; mt < 4; ++mt)
#pragma unroll
    for (int s = 0; s < 4; ++s) acc[mt][s] = (f32x4){0.f, 0.f, 0.f, 0.f};

  const size_t in_b = ((size_t)b * CCH) << 16;

#pragma unroll
  for (int chunk = 0; chunk < 2; ++chunk) {
    __syncthreads();                 // previous chunk's reads complete
    // ---- stage: item = (row, oct, px); lane loads 8 ci for one px ----
    for (int i = t; i < SROW * 4 * SPX; i += 256) {   // 1584 items
      int ro = i / SPX;              // row*4 + oct
      int px = i - ro * SPX;
      int row = ro >> 2, oct = ro & 3;
      int gr = row0 - 1 + row;
      int gx = px0g - 1 + px;
      bool okxy = (gr >= 0 && gr < HH && gx >= 0 && gx < WW);
      const float* gp = in + in_b + ((size_t)(chunk * 32 + oct * 8) << 16)
                        + (gr << 8) + gx;
      unsigned hs[8], ls[8];
#pragma unroll
      for (int e = 0; e < 8; ++e) {
        int ci = chunk * 32 + oct * 8 + e;
        float x = (okxy && ci < CCH) ? gp[(size_t)e << 16] : 0.f;
        unsigned u = __float_as_uint(x);
        unsigned hu = u & 0xFFFF0000u;          // trunc-split hi
        float lo = x - __uint_as_float(hu);     // exact residual
        unsigned ul = __float_as_uint(lo);
        hs[e] = hu >> 16;
        ls[e] = (ul + 0x7FFFu + ((ul >> 16) & 1u)) >> 16;   // rne lo
      }
      s16x8 hv, lv;
#pragma unroll
      for (int e = 0; e < 8; ++e) { hv[e] = (short)hs[e]; lv[e] = (short)ls[e]; }
      int swz = (px & 7) << 3;                  // 16B-granule XOR (8 shorts)
      int base_sh = (row * SPX + px) * 64;
      *(s16x8*)&xlds[base_sh + ((oct * 8) ^ swz)] = hv;
      *(s16x8*)&xlds[base_sh + ((32 + oct * 8) ^ swz)] = lv;
    }
    __syncthreads();

    // ---- 9 taps ----
#pragma unroll
    for (int tap = 0; tap < 9; ++tap) {
      const int dh = tap / 3 - 1;
      const int dw = tap % 3 - 1;
      s16x8 ah[4], al[4];
#pragma unroll
      for (int mt = 0; mt < 4; ++mt) {
        int cb = ((chunk * 9 + tap) * 4 + mt) * 2;
        ah[mt] = *(const s16x8*)(wf + (size_t)cb * 512 + lane * 8);
        al[mt] = *(const s16x8*)(wf + (size_t)(cb + 1) * 512 + lane * 8);
      }
      int rbase = (wv + 1 + dh) * (SPX * 64);
#pragma unroll
      for (int s = 0; s < 4; ++s) {
        int pixL = 1 + s * 16 + ln15 + dw;
        int bsh = rbase + pixL * 64;
        int swz = (pixL & 7) << 3;
        s16x8 bh = *(const s16x8*)&xlds[bsh + ((lg * 8) ^ swz)];
        s16x8 bl = *(const s16x8*)&xlds[bsh + ((32 + lg * 8) ^ swz)];
        __builtin_amdgcn_s_setprio(1);
#pragma unroll
        for (int mt = 0; mt < 4; ++mt) {
          acc[mt][s] = __builtin_amdgcn_mfma_f32_16x16x32_bf16(
              ah[mt], bh, acc[mt][s], 0, 0, 0);
          acc[mt][s] = __builtin_amdgcn_mfma_f32_16x16x32_bf16(
              ah[mt], bl, acc[mt][s], 0, 0, 0);
          acc[mt][s] = __builtin_amdgcn_mfma_f32_16x16x32_bf16(
              al[mt], bh, acc[mt][s], 0, 0, 0);
        }
        __builtin_amdgcn_s_setprio(0);
      }
    }
  }

  // ---- epilogue: bias + ReLU -> planar f32 (C/D: col=lane&15,
  // row=(lane>>4)*4+reg) ----
  int orow = row0 + wv;
#pragma unroll
  for (int s = 0; s < 4; ++s) {
    int px = px0g + s * 16 + ln15;
#pragma unroll
    for (int mt = 0; mt < 4; ++mt) {
#pragma unroll
      for (int reg = 0; reg < 4; ++reg) {
        int co = mt * 16 + lg * 4 + reg;
        if (co < CCH) {
          float v = fmaxf(acc[mt][s][reg] + b1[co], 0.f);
          x1p[(((size_t)b * CCH + co) << 16) + (orow << 8) + px] = v;
        }
      }
    }
  }
}

// ---------------- Kernel 2: conv3x3 (50->2) + softmax[:,1] + 4x4 pool ----
// Thread = 1 column x 4 output rows (= exactly one pool row); 6 input rows
// read once. Vertical sum in-register + 4-lane shfl_xor horizontal reduce,
// lane px%4==0 writes pool (+LeakyReLU). sm buffer eliminated.
__global__ __launch_bounds__(256) void conv2_pool_k(
    const float* __restrict__ x1p, const float* __restrict__ w2,
    const float* __restrict__ b2, float* __restrict__ pool) {
  int pb = blockIdx.x;                       // 1024 blocks = 8 XCD x 128
  int l = (pb & 7) * 128 + (pb >> 3);        // bijective chunked swizzle
  int b  = l >> 6;
  int rg = l & 63;
  int row0 = rg * 4;
  int px = threadIdx.x;

  float a0, a1, a2, a3, c0, c1, c2, c3;      // ch0 / ch1 per output row
  a0 = a1 = a2 = a3 = b2[0];
  c0 = c1 = c2 = c3 = b2[1];
  bool wm = px > 0, wp = px < WW - 1;

  const float* xb = x1p + (((size_t)b * CCH) << 16);

#define TAP(T, A, C) { \
    A = fmaf(wc0[3 * (T)], lf, A); A = fmaf(wc0[3 * (T) + 1], m, A); \
    A = fmaf(wc0[3 * (T) + 2], rt, A); \
    C = fmaf(wc1[3 * (T)], lf, C); C = fmaf(wc1[3 * (T) + 1], m, C); \
    C = fmaf(wc1[3 * (T) + 2], rt, C); }

#define ROW(IR, BODY) { \
    int gr = row0 - 1 + (IR); \
    if (gr >= 0 && gr < HH) { \
      const float* rp = xp + (gr << 8); \
      float m  = rp[px]; \
      float lf = wm ? rp[px - 1] : 0.f; \
      float rt = wp ? rp[px + 1] : 0.f; \
      BODY \
    } }

  for (int ci = 0; ci < CCH; ++ci) {
    const float* xp = xb + ((size_t)ci << 16);
    const float* wc0 = w2 + ci * 9;
    const float* wc1 = w2 + 450 + ci * 9;
    ROW(0, TAP(0, a0, c0))
    ROW(1, TAP(0, a1, c1) TAP(1, a0, c0))
    ROW(2, TAP(0, a2, c2) TAP(1, a1, c1) TAP(2, a0, c0))
    ROW(3, TAP(0, a3, c3) TAP(1, a2, c2) TAP(2, a1, c1))
    ROW(4, TAP(1, a3, c3) TAP(2, a2, c2))
    ROW(5, TAP(2, a3, c3))
  }
#undef ROW
#undef TAP

  float s = 1.f / (1.f + expf(a0 - c0)) + 1.f / (1.f + expf(a1 - c1))
          + 1.f / (1.f + expf(a2 - c2)) + 1.f / (1.f + expf(a3 - c3));
  s += __shfl_xor(s, 1);
  s += __shfl_xor(s, 2);
  if ((px & 3) == 0) {
    float p = s * (1.f / 16.f);
    pool[(size_t)b * 4096 + rg * 64 + (px >> 2)] = (p >= 0.f) ? p : 0.1f * p;
  }
}

// ---------------- Kernel 3: mix (25-tap) + per-batch top-240 sort --------
// 16 blocks x 1024 threads: mask computed inline from pool (L2-hot 16 KB),
// keys built directly; bitonic-4096 at 2 iters/phase (was 8).
__global__ __launch_bounds__(1024) void mixtopk_k(
    const float* __restrict__ pool, const float* __restrict__ wk,
    const float* __restrict__ bk, float* __restrict__ mask_out,
    float* __restrict__ ob, float* __restrict__ oh, float* __restrict__ ow,
    int* __restrict__ idx_ws) {
  __shared__ unsigned long long keys[4096];
  __shared__ int sidx[256];
  int b = blockIdx.x, t = threadIdx.x;

  const float* pb = pool + (size_t)b * 4096;
  for (int i = t; i < 4096; i += 1024) {
    int hs = i >> 6, ws = i & 63;
    float c = pb[i];
    float s = 0.f;
#pragma unroll
    for (int ki = 0; ki < 5; ++ki) {
#pragma unroll
      for (int kj = 0; kj < 5; ++kj) {
        int y = hs + ki - 2, x = ws + kj - 2;
        float win = (y >= 0 && y < HSZ && x >= 0 && x < WSZ)
                        ? pb[y * WSZ + x] : 0.f;
        int k = ki * 5 + kj;
        s += (wk[k] * c + bk[k]) * win;
      }
    }
    mask_out[(size_t)b * 4096 + i] = s;
    unsigned u = __float_as_uint(s);
    u = (u & 0x80000000u) ? ~u : (u | 0x80000000u);   // order-preserving
    u = ~u;                                            // ascending -> desc
    keys[i] = ((unsigned long long)u << 12) | (unsigned)i;
  }
  __syncthreads();

  for (int k = 2; k <= 4096; k <<= 1) {
    for (int j = k >> 1; j > 0; j >>= 1) {
      for (int m = t; m < 2048; m += 1024) {
        int i = ((m & ~(j - 1)) << 1) | (m & (j - 1));
        int l = i | j;
        bool up = ((i & k) == 0);
        unsigned long long a = keys[i], c = keys[l];
        if ((a > c) == up) { keys[i] = c; keys[l] = a; }
      }
      __syncthreads();
    }
  }

  if (t < 256) sidx[t] = (t < NTOP) ? (int)(keys[t] & 0xFFFu) : 0x7FFFFFFF;
  __syncthreads();
  for (int k = 2; k <= 256; k <<= 1) {
    for (int j = k >> 1; j > 0; j >>= 1) {
      if (t < 128) {
        int i = ((t & ~(j - 1)) << 1) | (t & (j - 1));
        int l = i | j;
        bool up = ((i & k) == 0);
        int a = sidx[i], c = sidx[l];
        if ((a > c) == up) { sidx[i] = c; sidx[l] = a; }
      }
      __syncthreads();
    }
  }

  if (t < NTOP) {
    int id = sidx[t];
    int o = b * NTOP + t;
    ob[o] = (float)b;
    oh[o] = (float)(id >> 6);
    ow[o] = (float)(id & 63);
    idx_ws[o] = id;
  }
}

// ---------------- Kernel 4: gather 6x6 patches (pad=1, stride=4) ---------
__global__ __launch_bounds__(256) void gather_patch_k(
    const float* __restrict__ in, const int* __restrict__ idx_ws,
    float* __restrict__ patches) {
  int p = blockIdx.x;
  int b = p / NTOP;
  int id = idx_ws[p];
  int h = id >> 6, w = id & 63;
  int y0 = h * 4 - 1, x0 = w * 4 - 1;
  const float* base = in + (size_t)b * CCH * 65536;
  float* op = patches + (size_t)p * (CCH * 36);
  for (int e = threadIdx.x; e < CCH * 36; e += 256) {
    int c = e / 36;
    int r = (e - c * 36) / 6;
    int col = e - c * 36 - r * 6;
    int y = y0 + r, x = x0 + col;
    float v = 0.f;
    if (y >= 0 && y < HH && x >= 0 && x < WW)
      v = base[(size_t)c * 65536 + y * WW + x];
    op[e] = v;
  }
}

extern "C" void kernel_launch(void* const* d_in, const int* in_sizes, int n_in,
                              void* d_out, int out_size, void* d_ws, size_t ws_size,
                              hipStream_t stream) {
  const float* out_lr = (const float*)d_in[0];
  const float* W1 = (const float*)d_in[1];
  const float* b1 = (const float*)d_in[2];
  const float* W2 = (const float*)d_in[3];
  const float* b2 = (const float*)d_in[4];
  const float* Wk = (const float*)d_in[5];
  const float* bk = (const float*)d_in[6];

  float* x1p  = (float*)d_ws;                 // 16*50*256*256 f32
  float* pool = x1p + (size_t)52428800;       // 16*64*64
  int*  idxb  = (int*)(pool + 65536);         // 16*240
  unsigned short* wfrag = (unsigned short*)(pool + 65536 + 3840);  // 73,728 bf16

  float* out    = (float*)d_out;
  float* o_patch = out;                        // 3840*50*36
  float* o_b    = out + (size_t)6912000;
  float* o_h    = o_b + 3840;
  float* o_w    = o_h + 3840;
  float* o_mask = o_w + 3840;                  // 16*4096

  prep_wfrag_k<<<144, 64, 0, stream>>>(W1, wfrag);
  conv1_mfma_k<<<BATCH * 64 * 4, 256, 0, stream>>>(out_lr, wfrag, b1, x1p);
  conv2_pool_k<<<BATCH * 64, 256, 0, stream>>>(x1p, W2, b2, pool);
  mixtopk_k<<<BATCH, 1024, 0, stream>>>(pool, Wk, bk, o_mask, o_b, o_h, o_w, idxb);
  gather_patch_k<<<BATCH * NTOP, 256, 0, stream>>>(out_lr, idxb, o_patch);
}